// Round 1
// baseline (73.225 us; speedup 1.0000x reference)
//
#include <hip/hip_runtime.h>

// Deformable depthwise conv1d (fp32), MI355X.
// x: (B=8, C=512, T=4096), weight: (C,7), offset_w: (C*7,1,7), offset_b: (C*7,)
// out: (B, C, T_out=4090)
//
// offs[b,c,k,t] = sum_j x[b,c,t+j] * offset_w[(c*7+k)*7 + j] + offset_b[c*7+k]
// pos = t + k + offs; bilinear gather from x[b,c,:] with zero outside [0,T-1]
// out[b,c,t] = sum_k sampled[k] * weight[c,k]

constexpr int B_ = 8;
constexpr int C_ = 512;
constexpr int T_ = 4096;
constexpr int K_ = 7;
constexpr int T_OUT = T_ - K_ + 1;  // 4090
constexpr int BLOCK = 256;

__global__ __launch_bounds__(BLOCK)
void deform_dwconv1d_kernel(const float* __restrict__ x,
                            const float* __restrict__ weight,
                            const float* __restrict__ offset_w,
                            const float* __restrict__ offset_b,
                            float* __restrict__ out)
{
    __shared__ float row[T_];   // one (b,c) row: 16 KB

    const int bc  = blockIdx.x;        // b*C + c
    const int c   = bc & (C_ - 1);
    const int tid = threadIdx.x;

    // ---- stage x[b,c,:] into LDS (float4, coalesced) ----
    const float4* src = reinterpret_cast<const float4*>(x + (size_t)bc * T_);
    float4* dst = reinterpret_cast<float4*>(row);
    #pragma unroll
    for (int i = 0; i < T_ / 4 / BLOCK; ++i)   // 4 iters
        dst[tid + i * BLOCK] = src[tid + i * BLOCK];

    // ---- per-channel weights (block-uniform -> scalar regs) ----
    float ow[K_ * K_];
    #pragma unroll
    for (int i = 0; i < K_ * K_; ++i) ow[i] = offset_w[c * K_ * K_ + i];
    float wgt[K_], ob[K_];
    #pragma unroll
    for (int k = 0; k < K_; ++k) {
        wgt[k] = weight[c * K_ + k];
        ob[k]  = offset_b[c * K_ + k];
    }

    __syncthreads();

    float* orow = out + (size_t)bc * T_OUT;

    #pragma unroll
    for (int it = 0; it < (T_OUT + BLOCK - 1) / BLOCK; ++it) {  // 16 iters
        const int t = it * BLOCK + tid;
        if (t < T_OUT) {
            // window x[t..t+6] (t+6 <= 4095, always in-bounds)
            float win[K_];
            #pragma unroll
            for (int j = 0; j < K_; ++j) win[j] = row[t + j];

            float acc = 0.0f;
            #pragma unroll
            for (int k = 0; k < K_; ++k) {
                // offset conv
                float o = ob[k];
                #pragma unroll
                for (int j = 0; j < K_; ++j)
                    o = fmaf(win[j], ow[k * K_ + j], o);

                // bilinear sample at pos = t + k + o
                const float pos = (float)(t + k) + o;
                const float f   = floorf(pos);
                const int   i0  = (int)f;
                const float w1  = pos - f;

                const int c0 = min(max(i0, 0), T_ - 1);
                const int c1 = min(max(i0 + 1, 0), T_ - 1);
                float g0 = row[c0];
                float g1 = row[c1];
                g0 = (i0 >= 0 && i0 <= T_ - 1) ? g0 : 0.0f;
                g1 = (i0 >= -1 && i0 + 1 <= T_ - 1) ? g1 : 0.0f;

                const float s = g0 * (1.0f - w1) + g1 * w1;
                acc = fmaf(s, wgt[k], acc);
            }
            orow[t] = acc;
        }
    }
}

extern "C" void kernel_launch(void* const* d_in, const int* in_sizes, int n_in,
                              void* d_out, int out_size, void* d_ws, size_t ws_size,
                              hipStream_t stream) {
    const float* x        = (const float*)d_in[0];
    const float* weight   = (const float*)d_in[1];
    const float* offset_w = (const float*)d_in[2];
    const float* offset_b = (const float*)d_in[3];
    float* out = (float*)d_out;

    deform_dwconv1d_kernel<<<B_ * C_, BLOCK, 0, stream>>>(
        x, weight, offset_w, offset_b, out);
}

// Round 2
// 53.065 us; speedup vs baseline: 1.3799x; 1.3799x over previous
//
#include <hip/hip_runtime.h>

// Deformable depthwise conv1d (fp32), MI355X.
// Round 2: zero-padded LDS row + med3 float clamp (kills per-tap cndmask
// guards), 2 consecutive t per thread with float2 loads/stores.

constexpr int B_ = 8;
constexpr int C_ = 512;
constexpr int T_ = 4096;
constexpr int K_ = 7;
constexpr int T_OUT = T_ - K_ + 1;      // 4090
constexpr int NPAIR = T_OUT / 2;        // 2045 (T_OUT is even)
constexpr int BLOCK = 256;
constexpr int P_ = 16;                  // zero pad each side (>> max |offset|)
constexpr int ROWP = P_ + T_ + P_;      // 4128 floats = 16.5 KB

__global__ __launch_bounds__(BLOCK)
void deform_dwconv1d_kernel(const float* __restrict__ x,
                            const float* __restrict__ weight,
                            const float* __restrict__ offset_w,
                            const float* __restrict__ offset_b,
                            float* __restrict__ out)
{
    __shared__ float rowp[ROWP];

    const int bc  = blockIdx.x;        // b*C + c
    const int c   = bc & (C_ - 1);
    const int tid = threadIdx.x;

    // zero the pads
    if (tid < P_) {
        rowp[tid] = 0.0f;
        rowp[P_ + T_ + tid] = 0.0f;
    }

    // stage x[b,c,:] into rowp[P_ ..] (float4, coalesced; rowp+16 is 64B-aligned)
    const float4* src = reinterpret_cast<const float4*>(x + (size_t)bc * T_);
    float4* dst = reinterpret_cast<float4*>(rowp + P_);
    #pragma unroll
    for (int i = 0; i < T_ / 4 / BLOCK; ++i)   // 4 iters
        dst[tid + i * BLOCK] = src[tid + i * BLOCK];

    // per-channel weights: uniform addresses -> scalar loads / SGPRs
    float ow[K_ * K_];
    #pragma unroll
    for (int i = 0; i < K_ * K_; ++i) ow[i] = offset_w[c * K_ * K_ + i];
    float wgt[K_], obk[K_];
    #pragma unroll
    for (int k = 0; k < K_; ++k) {
        wgt[k] = weight[c * K_ + k];
        obk[k] = offset_b[c * K_ + k] + (float)k;   // fold +k into the bias
    }

    __syncthreads();

    float* orow = out + (size_t)bc * T_OUT;
    constexpr float HI = (float)(ROWP - 2);   // 4126: rowp[HI], rowp[HI+1] are pad zeros

    #pragma unroll
    for (int it = 0; it < (NPAIR + BLOCK - 1) / BLOCK; ++it) {  // 8 iters
        const int pt = it * BLOCK + tid;
        if (pt < NPAIR) {
            const int t0 = 2 * pt;

            // window x[t0 .. t0+7] (8B-aligned float2 reads, 2-way bank alias = free)
            const float2* wp = reinterpret_cast<const float2*>(rowp + P_ + t0);
            float2 a0 = wp[0], a1 = wp[1], a2 = wp[2], a3 = wp[3];
            float w[8] = {a0.x, a0.y, a1.x, a1.y, a2.x, a2.y, a3.x, a3.y};

            const float tfA = (float)(t0 + P_);
            const float tfB = tfA + 1.0f;
            float accA = 0.0f, accB = 0.0f;

            #pragma unroll
            for (int k = 0; k < K_; ++k) {
                // offset conv, accumulator seeded with bias + k + t + P
                float oA = obk[k] + tfA;
                float oB = obk[k] + tfB;
                #pragma unroll
                for (int j = 0; j < K_; ++j) {
                    oA = fmaf(w[j],     ow[k * K_ + j], oA);
                    oB = fmaf(w[j + 1], ow[k * K_ + j], oB);
                }
                // oA/oB are now padded positions; clamp into [0, 4126] (v_med3)
                float pA = fminf(fmaxf(oA, 0.0f), HI);
                float pB = fminf(fmaxf(oB, 0.0f), HI);
                float fA = floorf(pA), fB = floorf(pB);
                int   iA = (int)fA,   iB = (int)fB;
                float uA = pA - fA,   uB = pB - fB;

                // fused ds_read2_b32 pairs
                float g0A = rowp[iA], g1A = rowp[iA + 1];
                float g0B = rowp[iB], g1B = rowp[iB + 1];

                float sA = fmaf(uA, g1A - g0A, g0A);
                float sB = fmaf(uB, g1B - g0B, g0B);
                accA = fmaf(sA, wgt[k], accA);
                accB = fmaf(sB, wgt[k], accB);
            }
            *reinterpret_cast<float2*>(orow + t0) = make_float2(accA, accB);
        }
    }
}

extern "C" void kernel_launch(void* const* d_in, const int* in_sizes, int n_in,
                              void* d_out, int out_size, void* d_ws, size_t ws_size,
                              hipStream_t stream) {
    const float* x        = (const float*)d_in[0];
    const float* weight   = (const float*)d_in[1];
    const float* offset_w = (const float*)d_in[2];
    const float* offset_b = (const float*)d_in[3];
    float* out = (float*)d_out;

    deform_dwconv1d_kernel<<<B_ * C_, BLOCK, 0, stream>>>(
        x, weight, offset_w, offset_b, out);
}

// Round 3
// 53.028 us; speedup vs baseline: 1.3809x; 1.0007x over previous
//
#include <hip/hip_runtime.h>

// Deformable depthwise conv1d (fp32), MI355X.
// Round 3: strided 2-outputs/thread (tA, tA+256) -> all LDS traffic back to
// lane-stride-1 (conflict-free); packed v_pk_fma_f32 offset conv via
// ext_vector float2; fract/trunc trick for bilinear decompose.

constexpr int B_ = 8;
constexpr int C_ = 512;
constexpr int T_ = 4096;
constexpr int K_ = 7;
constexpr int T_OUT = T_ - K_ + 1;      // 4090
constexpr int BLOCK = 256;
constexpr int P_ = 16;                  // zero pad each side (>> max |offset|)
constexpr int ROWP = P_ + T_ + P_;      // 4128 floats = 16.5 KB
constexpr int SPAN = 2 * BLOCK;         // 512 t per outer iter

typedef float v2f __attribute__((ext_vector_type(2)));

__global__ __launch_bounds__(BLOCK)
void deform_dwconv1d_kernel(const float* __restrict__ x,
                            const float* __restrict__ weight,
                            const float* __restrict__ offset_w,
                            const float* __restrict__ offset_b,
                            float* __restrict__ out)
{
    __shared__ float rowp[ROWP];

    const int bc  = blockIdx.x;        // b*C + c
    const int c   = bc & (C_ - 1);
    const int tid = threadIdx.x;

    // zero the pads
    if (tid < P_) {
        rowp[tid] = 0.0f;
        rowp[P_ + T_ + tid] = 0.0f;
    }

    // stage x[b,c,:] into rowp[P_ ..] (float4, coalesced)
    const float4* src = reinterpret_cast<const float4*>(x + (size_t)bc * T_);
    float4* dst = reinterpret_cast<float4*>(rowp + P_);
    #pragma unroll
    for (int i = 0; i < T_ / 4 / BLOCK; ++i)   // 4 iters
        dst[tid + i * BLOCK] = src[tid + i * BLOCK];

    // per-channel weights: uniform addresses -> scalar loads / SGPRs
    float ow[K_ * K_];
    #pragma unroll
    for (int i = 0; i < K_ * K_; ++i) ow[i] = offset_w[c * K_ * K_ + i];
    float wgt[K_], obk[K_];
    #pragma unroll
    for (int k = 0; k < K_; ++k) {
        wgt[k] = weight[c * K_ + k];
        obk[k] = offset_b[c * K_ + k] + (float)k;   // fold +k into the bias
    }

    __syncthreads();

    float* orow = out + (size_t)bc * T_OUT;
    constexpr float HI = (float)(ROWP - 2);   // 4126: rowp[HI..HI+1] are pad zeros

    #pragma unroll
    for (int it = 0; it < 8; ++it) {
        const int tA = it * SPAN + tid;            // lane-stride-1
        const int tB = tA + BLOCK;                 // lane-stride-1

        // windows (stride-1 across lanes -> conflict-free, fuses to ds_read2)
        float wA[K_ + 1], wB[K_ + 1];
        #pragma unroll
        for (int j = 0; j < K_; ++j) {
            wA[j] = rowp[P_ + tA + j];
            wB[j] = rowp[P_ + tB + j];
        }

        const v2f tf = {(float)(tA + P_), (float)(tB + P_)};
        float accA = 0.0f, accB = 0.0f;

        #pragma unroll
        for (int k = 0; k < K_; ++k) {
            // packed offset conv; accumulator seeded with bias + k + t + P
            v2f o = tf + obk[k];
            #pragma unroll
            for (int j = 0; j < K_; ++j) {
                v2f w2 = {wA[j], wB[j]};
                v2f m2 = {ow[k * K_ + j], ow[k * K_ + j]};
                o = __builtin_elementwise_fma(w2, m2, o);
            }

            // clamp to padded range (v_med3), fract/trunc bilinear decompose
            const float pA = fminf(fmaxf(o.x, 0.0f), HI);
            const float pB = fminf(fmaxf(o.y, 0.0f), HI);
            const int   iA = (int)pA;              // p >= 0: trunc == floor
            const int   iB = (int)pB;
            const float uA = pA - (float)iA;
            const float uB = pB - (float)iB;

            // fused ds_read2_b32 pairs; lane addrs ~stride-1 -> conflict-free
            const float g0A = rowp[iA], g1A = rowp[iA + 1];
            const float g0B = rowp[iB], g1B = rowp[iB + 1];

            const float sA = fmaf(uA, g1A - g0A, g0A);
            const float sB = fmaf(uB, g1B - g0B, g0B);
            accA = fmaf(sA, wgt[k], accA);
            accB = fmaf(sB, wgt[k], accB);
        }

        orow[tA] = accA;                            // tA <= 3839 always valid
        if (it < 7 || tid < T_OUT - 7 * SPAN - BLOCK)   // tB < 4090
            orow[tB] = accB;
    }
}

extern "C" void kernel_launch(void* const* d_in, const int* in_sizes, int n_in,
                              void* d_out, int out_size, void* d_ws, size_t ws_size,
                              hipStream_t stream) {
    const float* x        = (const float*)d_in[0];
    const float* weight   = (const float*)d_in[1];
    const float* offset_w = (const float*)d_in[2];
    const float* offset_b = (const float*)d_in[3];
    float* out = (float*)d_out;

    deform_dwconv1d_kernel<<<B_ * C_, BLOCK, 0, stream>>>(
        x, weight, offset_w, offset_b, out);
}